// Round 19
// baseline (35.372 us; speedup 1.0000x reference)
//
#include <hip/hip_runtime.h>
#include <math.h>

#define BB 4
#define TQ 256
#define TV 256
#define DD 512
#define UU 128
#define NEGV (-1e9f)

__device__ __forceinline__ float fast_rcp(float x) {
    return __builtin_amdgcn_rcpf(x);   // v_rcp_f32
}
__device__ __forceinline__ float4 f4fma(float s, float4 v, float4 a) {
    a.x = fmaf(s, v.x, a.x); a.y = fmaf(s, v.y, a.y);
    a.z = fmaf(s, v.z, a.z); a.w = fmaf(s, v.w, a.w);
    return a;
}

// ---------------- kernel 1: projections (R18 body, unchanged; launched 2x as probe) ----------------
__global__ __launch_bounds__(256) void proj_kernel(
    const float* __restrict__ query, const float* __restrict__ value,
    const float* __restrict__ W1, const float* __restrict__ W2,
    float* __restrict__ eqp /* [B*TQ][U] = exp(2q) */,
    float* __restrict__ ekT /* [B][U][TV] = exp(2k) */) {
    int bid = blockIdx.x;              // 0..255
    int which = bid >> 7;              // 0 = q, 1 = k
    int row0 = (bid & 127) * 8;
    const float* X = which ? value : query;
    const float* W = which ? W2 : W1;
    int tid = threadIdx.x;
    int ug = tid & 31;                 // u-group: u0 = ug*4
    int kc = tid >> 5;                 // K-eighth 0..7 (64 d each)
    int u0 = ug * 4;

    __shared__ float xs[8 * DD];       // 16 KB: 8 input rows
    __shared__ float part[7][8][UU];   // 28 KB: split-K partials

    {   // stage 8 rows via float4, coalesced
        const float4* src = (const float4*)(X + (size_t)row0 * DD);
        float4* dst = (float4*)xs;
        #pragma unroll
        for (int i = 0; i < 4; ++i) dst[tid + 256 * i] = src[tid + 256 * i];
    }
    __syncthreads();

    const float* Wb = W + (size_t)(kc * 64) * UU + u0;
    float4 acc0 = make_float4(0.f,0.f,0.f,0.f), acc1 = acc0, acc2 = acc0,
           acc3 = acc0, acc4 = acc0, acc5 = acc0, acc6 = acc0, acc7 = acc0;
    #pragma unroll 4
    for (int c = 0; c < 16; ++c) {     // 16 chunks x 4 d
        float4 x0 = ((const float4*)(xs + 0 * DD + kc * 64))[c];
        float4 x1 = ((const float4*)(xs + 1 * DD + kc * 64))[c];
        float4 x2 = ((const float4*)(xs + 2 * DD + kc * 64))[c];
        float4 x3 = ((const float4*)(xs + 3 * DD + kc * 64))[c];
        float4 x4 = ((const float4*)(xs + 4 * DD + kc * 64))[c];
        float4 x5 = ((const float4*)(xs + 5 * DD + kc * 64))[c];
        float4 x6 = ((const float4*)(xs + 6 * DD + kc * 64))[c];
        float4 x7 = ((const float4*)(xs + 7 * DD + kc * 64))[c];
        float4 w0 = *(const float4*)(Wb + (size_t)(c * 4 + 0) * UU);
        float4 w1 = *(const float4*)(Wb + (size_t)(c * 4 + 1) * UU);
        float4 w2 = *(const float4*)(Wb + (size_t)(c * 4 + 2) * UU);
        float4 w3 = *(const float4*)(Wb + (size_t)(c * 4 + 3) * UU);
        acc0 = f4fma(x0.x, w0, f4fma(x0.y, w1, f4fma(x0.z, w2, f4fma(x0.w, w3, acc0))));
        acc1 = f4fma(x1.x, w0, f4fma(x1.y, w1, f4fma(x1.z, w2, f4fma(x1.w, w3, acc1))));
        acc2 = f4fma(x2.x, w0, f4fma(x2.y, w1, f4fma(x2.z, w2, f4fma(x2.w, w3, acc2))));
        acc3 = f4fma(x3.x, w0, f4fma(x3.y, w1, f4fma(x3.z, w2, f4fma(x3.w, w3, acc3))));
        acc4 = f4fma(x4.x, w0, f4fma(x4.y, w1, f4fma(x4.z, w2, f4fma(x4.w, w3, acc4))));
        acc5 = f4fma(x5.x, w0, f4fma(x5.y, w1, f4fma(x5.z, w2, f4fma(x5.w, w3, acc5))));
        acc6 = f4fma(x6.x, w0, f4fma(x6.y, w1, f4fma(x6.z, w2, f4fma(x6.w, w3, acc6))));
        acc7 = f4fma(x7.x, w0, f4fma(x7.y, w1, f4fma(x7.z, w2, f4fma(x7.w, w3, acc7))));
    }
    __syncthreads();
    if (kc) {
        ((float4*)&part[kc - 1][0][0])[ug] = acc0;
        ((float4*)&part[kc - 1][1][0])[ug] = acc1;
        ((float4*)&part[kc - 1][2][0])[ug] = acc2;
        ((float4*)&part[kc - 1][3][0])[ug] = acc3;
        ((float4*)&part[kc - 1][4][0])[ug] = acc4;
        ((float4*)&part[kc - 1][5][0])[ug] = acc5;
        ((float4*)&part[kc - 1][6][0])[ug] = acc6;
        ((float4*)&part[kc - 1][7][0])[ug] = acc7;
    }
    __syncthreads();
    if (!kc) {
        #pragma unroll
        for (int j = 0; j < 7; ++j) {
            float4 p;
            p = ((float4*)&part[j][0][0])[ug]; acc0.x+=p.x; acc0.y+=p.y; acc0.z+=p.z; acc0.w+=p.w;
            p = ((float4*)&part[j][1][0])[ug]; acc1.x+=p.x; acc1.y+=p.y; acc1.z+=p.z; acc1.w+=p.w;
            p = ((float4*)&part[j][2][0])[ug]; acc2.x+=p.x; acc2.y+=p.y; acc2.z+=p.z; acc2.w+=p.w;
            p = ((float4*)&part[j][3][0])[ug]; acc3.x+=p.x; acc3.y+=p.y; acc3.z+=p.z; acc3.w+=p.w;
            p = ((float4*)&part[j][4][0])[ug]; acc4.x+=p.x; acc4.y+=p.y; acc4.z+=p.z; acc4.w+=p.w;
            p = ((float4*)&part[j][5][0])[ug]; acc5.x+=p.x; acc5.y+=p.y; acc5.z+=p.z; acc5.w+=p.w;
            p = ((float4*)&part[j][6][0])[ug]; acc6.x+=p.x; acc6.y+=p.y; acc6.z+=p.z; acc6.w+=p.w;
            p = ((float4*)&part[j][7][0])[ug]; acc7.x+=p.x; acc7.y+=p.y; acc7.z+=p.z; acc7.w+=p.w;
        }
        #define EXP4(A) A.x=__expf(2.f*A.x); A.y=__expf(2.f*A.y); A.z=__expf(2.f*A.z); A.w=__expf(2.f*A.w);
        EXP4(acc0) EXP4(acc1) EXP4(acc2) EXP4(acc3)
        EXP4(acc4) EXP4(acc5) EXP4(acc6) EXP4(acc7)
        if (which == 0) {
            float4* p = (float4*)(eqp + (size_t)row0 * UU + u0);
            p[0*(UU/4)] = acc0; p[1*(UU/4)] = acc1; p[2*(UU/4)] = acc2; p[3*(UU/4)] = acc3;
            p[4*(UU/4)] = acc4; p[5*(UU/4)] = acc5; p[6*(UU/4)] = acc6; p[7*(UU/4)] = acc7;
        } else {
            int b = row0 >> 8, v0 = row0 & 255;
            #define KSTORE(J, CX) { \
                float4 lo = make_float4(acc0.CX, acc1.CX, acc2.CX, acc3.CX); \
                float4 hi = make_float4(acc4.CX, acc5.CX, acc6.CX, acc7.CX); \
                float* dst = ekT + ((size_t)(b * UU) + u0 + J) * TV + v0;    \
                *(float4*)dst = lo; *(float4*)(dst + 4) = hi; }
            KSTORE(0, x) KSTORE(1, y) KSTORE(2, z) KSTORE(3, w)
        }
    }
}

// ---------------- kernel 2: FUSED attn; phase-B combine FLATTENED (1 barrier, was 7) ----------------
__global__ __launch_bounds__(1024) void attn_kernel(
    const float* __restrict__ eqp, const float* __restrict__ ekT,
    const float* __restrict__ scale, const unsigned char* __restrict__ m,
    const float* __restrict__ value,
    float* __restrict__ ctx, float* __restrict__ weights) {
    int blk = blockIdx.x;              // 0..255
    int b = blk >> 6;
    int q0 = (blk & 63) * 4;
    int tid = threadIdx.x;             // 0..1023
    int lane = tid & 63;

    __shared__ float eq4[4][UU];       // 2 KB
    __shared__ float sc2[UU];          // 512 B
    __shared__ union {                 // 56 KB (phases sync-separated)
        float pbA[8][4][TV];           // phase A partials (32 KB)
        float4 pbB[7][4][128];         // phase B flat partials (56 KB)
    } un;
    __shared__ float sv[4][TV];        // 4 KB
    __shared__ float redM[4][4], redS[4][4];
    __shared__ int flagF, flagB;
    // total static LDS ~64.1 KB... (56+4+2+0.5+0.13) = 62.7 KB <= 64 KB

    if (tid == 0) { flagF = 0; flagB = 0; }
    __syncthreads();
    if (tid < 128) {
        ((float4*)eq4)[tid] = ((const float4*)(eqp + (size_t)(b * TQ + q0) * UU))[tid];
    } else if (tid < 160) {
        float4 s = ((const float4*)scale)[tid - 128];
        ((float4*)sc2)[tid - 128] = make_float4(-2.f*s.x, -2.f*s.y, -2.f*s.z, -2.f*s.w);
    }
    if (tid >= 256 && tid < 512) {
        uchar4 c4 = ((const uchar4*)m)[tid - 256];
        if (c4.w == 0x3f) flagF = 1;
        if (c4.y | c4.z | c4.w) flagB = 1;
    }
    __syncthreads();

    // ---- phase A ----
    {
        int vp = tid & 127;
        int h = tid >> 7;
        const float2* kb2 = (const float2*)(ekT + ((size_t)b * UU + h * 16) * TV) + vp;
        float ax0=0.f, ay0=0.f, ax1=0.f, ay1=0.f;
        float ax2=0.f, ay2=0.f, ax3=0.f, ay3=0.f;
        #pragma unroll
        for (int c = 0; c < 4; ++c) {
            float4 e0 = ((const float4*)&eq4[0][0])[h * 4 + c];
            float4 e1 = ((const float4*)&eq4[1][0])[h * 4 + c];
            float4 e2 = ((const float4*)&eq4[2][0])[h * 4 + c];
            float4 e3 = ((const float4*)&eq4[3][0])[h * 4 + c];
            float4 sc = ((const float4*)sc2)[h * 4 + c];
            #define ASTEP(J, CX) { \
                float2 ek = kb2[(size_t)(c * 4 + J) * (TV / 2)]; \
                ax0 = fmaf(sc.CX, fast_rcp(fmaf(e0.CX, ek.x, 1.f)), ax0); \
                ay0 = fmaf(sc.CX, fast_rcp(fmaf(e0.CX, ek.y, 1.f)), ay0); \
                ax1 = fmaf(sc.CX, fast_rcp(fmaf(e1.CX, ek.x, 1.f)), ax1); \
                ay1 = fmaf(sc.CX, fast_rcp(fmaf(e1.CX, ek.y, 1.f)), ay1); \
                ax2 = fmaf(sc.CX, fast_rcp(fmaf(e2.CX, ek.x, 1.f)), ax2); \
                ay2 = fmaf(sc.CX, fast_rcp(fmaf(e2.CX, ek.y, 1.f)), ay2); \
                ax3 = fmaf(sc.CX, fast_rcp(fmaf(e3.CX, ek.x, 1.f)), ax3); \
                ay3 = fmaf(sc.CX, fast_rcp(fmaf(e3.CX, ek.y, 1.f)), ay3); }
            ASTEP(0, x) ASTEP(1, y) ASTEP(2, z) ASTEP(3, w)
        }
        ((float2*)&un.pbA[h][0][0])[vp] = make_float2(ax0, ay0);
        ((float2*)&un.pbA[h][1][0])[vp] = make_float2(ax1, ay1);
        ((float2*)&un.pbA[h][2][0])[vp] = make_float2(ax2, ay2);
        ((float2*)&un.pbA[h][3][0])[vp] = make_float2(ax3, ay3);
        __syncthreads();
        if (h < 4) {
            float2 s = make_float2(0.f, 0.f);
            #pragma unroll
            for (int g = 0; g < 8; ++g) {
                float2 p = ((float2*)&un.pbA[g][h][0])[vp];
                s.x += p.x; s.y += p.y;
            }
            ((float2*)&sv[h][0])[vp] = s;
        }
        __syncthreads();
    }

    // ---- masked softmax: gated to waves 0-3; barriers outside branches ----
    {
        int v = tid & 255;
        float s0, s1, s2, s3, e0, e1, e2, e3;
        if (tid < 256) {
            float mk;
            {
                int idx = b * TV + v;
                bool ok;
                if (flagF)      ok = (m[4 * idx + 3] != 0);
                else if (flagB) ok = (m[idx] != 0);
                else            ok = (m[4 * idx] != 0);
                mk = ok ? __builtin_inff() : NEGV;
            }
            s0 = fminf(sv[0][v], mk); s1 = fminf(sv[1][v], mk);
            s2 = fminf(sv[2][v], mk); s3 = fminf(sv[3][v], mk);
            float m0 = s0, m1 = s1, m2 = s2, m3 = s3;
            #pragma unroll
            for (int off = 32; off >= 1; off >>= 1) {
                m0 = fmaxf(m0, __shfl_xor(m0, off));
                m1 = fmaxf(m1, __shfl_xor(m1, off));
                m2 = fmaxf(m2, __shfl_xor(m2, off));
                m3 = fmaxf(m3, __shfl_xor(m3, off));
            }
            int wid = tid >> 6;
            if (lane == 0) {
                redM[0][wid] = m0; redM[1][wid] = m1;
                redM[2][wid] = m2; redM[3][wid] = m3;
            }
        }
        __syncthreads();
        if (tid < 256) {
            float f0 = fmaxf(fmaxf(redM[0][0], redM[0][1]), fmaxf(redM[0][2], redM[0][3]));
            float f1 = fmaxf(fmaxf(redM[1][0], redM[1][1]), fmaxf(redM[1][2], redM[1][3]));
            float f2 = fmaxf(fmaxf(redM[2][0], redM[2][1]), fmaxf(redM[2][2], redM[2][3]));
            float f3 = fmaxf(fmaxf(redM[3][0], redM[3][1]), fmaxf(redM[3][2], redM[3][3]));
            e0 = __expf(s0 - f0); e1 = __expf(s1 - f1);
            e2 = __expf(s2 - f2); e3 = __expf(s3 - f3);
            float t0 = e0, t1 = e1, t2 = e2, t3 = e3;
            #pragma unroll
            for (int off = 32; off >= 1; off >>= 1) {
                t0 += __shfl_xor(t0, off); t1 += __shfl_xor(t1, off);
                t2 += __shfl_xor(t2, off); t3 += __shfl_xor(t3, off);
            }
            int wid = tid >> 6;
            if (lane == 0) {
                redS[0][wid] = t0; redS[1][wid] = t1;
                redS[2][wid] = t2; redS[3][wid] = t3;
            }
        }
        __syncthreads();
        if (tid < 256) {
            float r0 = fast_rcp((redS[0][0] + redS[0][1]) + (redS[0][2] + redS[0][3]));
            float r1 = fast_rcp((redS[1][0] + redS[1][1]) + (redS[1][2] + redS[1][3]));
            float r2 = fast_rcp((redS[2][0] + redS[2][1]) + (redS[2][2] + redS[2][3]));
            float r3 = fast_rcp((redS[3][0] + redS[3][1]) + (redS[3][2] + redS[3][3]));
            float w0 = e0 * r0, w1 = e1 * r1, w2 = e2 * r2, w3 = e3 * r3;
            float* wp = weights + (size_t)(b * TQ + q0) * TV + v;
            wp[0 * TV] = w0; wp[1 * TV] = w1; wp[2 * TV] = w2; wp[3 * TV] = w3;
            sv[0][v] = w0; sv[1][v] = w1; sv[2][v] = w2; sv[3][v] = w3;
        }
        __syncthreads();
    }

    // ---- phase B: flat combine (vh 1..7 write pbB; 1 barrier; vh 0 reduces) ----
    {
        int df = tid & 127;
        int vh = tid >> 7;
        const float4* vb4 = (const float4*)(value + ((size_t)b * TV + vh * 32) * DD) + df;
        float4 c0 = make_float4(0.f,0.f,0.f,0.f), c1 = c0, c2 = c0, c3 = c0;
        #pragma unroll
        for (int vc = 0; vc < 8; ++vc) {
            float4 w0 = ((const float4*)&sv[0][0])[vh * 8 + vc];
            float4 w1 = ((const float4*)&sv[1][0])[vh * 8 + vc];
            float4 w2 = ((const float4*)&sv[2][0])[vh * 8 + vc];
            float4 w3 = ((const float4*)&sv[3][0])[vh * 8 + vc];
            #define BSTEP(J, CX) { \
                float4 vv = vb4[(size_t)(vc * 4 + J) * (DD / 4)]; \
                c0 = f4fma(w0.CX, vv, c0); c1 = f4fma(w1.CX, vv, c1); \
                c2 = f4fma(w2.CX, vv, c2); c3 = f4fma(w3.CX, vv, c3); }
            BSTEP(0, x) BSTEP(1, y) BSTEP(2, z) BSTEP(3, w)
        }
        // pbA is dead (last read in phase A, fenced by softmax barriers);
        // pbB does not alias sv -> no barrier needed before the writes.
        if (vh > 0) {
            un.pbB[vh-1][0][df] = c0; un.pbB[vh-1][1][df] = c1;
            un.pbB[vh-1][2][df] = c2; un.pbB[vh-1][3][df] = c3;
        }
        __syncthreads();
        if (vh == 0) {
            #pragma unroll
            for (int j = 0; j < 7; ++j) {
                float4 p;
                p = un.pbB[j][0][df]; c0.x+=p.x; c0.y+=p.y; c0.z+=p.z; c0.w+=p.w;
                p = un.pbB[j][1][df]; c1.x+=p.x; c1.y+=p.y; c1.z+=p.z; c1.w+=p.w;
                p = un.pbB[j][2][df]; c2.x+=p.x; c2.y+=p.y; c2.z+=p.z; c2.w+=p.w;
                p = un.pbB[j][3][df]; c3.x+=p.x; c3.y+=p.y; c3.z+=p.z; c3.w+=p.w;
            }
            ((float4*)(ctx + (size_t)(b * TQ + q0 + 0) * DD))[df] = c0;
            ((float4*)(ctx + (size_t)(b * TQ + q0 + 1) * DD))[df] = c1;
            ((float4*)(ctx + (size_t)(b * TQ + q0 + 2) * DD))[df] = c2;
            ((float4*)(ctx + (size_t)(b * TQ + q0 + 3) * DD))[df] = c3;
        }
    }
}

extern "C" void kernel_launch(void* const* d_in, const int* in_sizes, int n_in,
                              void* d_out, int out_size, void* d_ws, size_t ws_size,
                              hipStream_t stream) {
    const float* query = (const float*)d_in[0];
    const float* value = (const float*)d_in[1];
    const unsigned char* mask = (const unsigned char*)d_in[2];
    const float* W1 = (const float*)d_in[3];
    const float* W2 = (const float*)d_in[4];
    const float* scale = (const float*)d_in[5];

    float* ctx = (float*)d_out;                              // [B,TQ,D]
    float* weights = (float*)d_out + (size_t)BB * TQ * DD;   // [B,TQ,TV]

    float* eqp = (float*)d_ws;                               // 512 KB
    float* ekT = eqp + (size_t)BB * TQ * UU;                 // 512 KB

    proj_kernel<<<256, 256, 0, stream>>>(query, value, W1, W2, eqp, ekT);
    // probe: second identical (idempotent) proj launch isolates proj's cost:
    // proj_us ~= dur_us(this round) - 26.5 (R18 baseline) + delta_attn_trim
    proj_kernel<<<256, 256, 0, stream>>>(query, value, W1, W2, eqp, ekT);
    attn_kernel<<<256, 1024, 0, stream>>>(eqp, ekT, scale, mask, value, ctx, weights);
}

// Round 20
// 29.628 us; speedup vs baseline: 1.1939x; 1.1939x over previous
//
#include <hip/hip_runtime.h>
#include <math.h>

#define BB 4
#define TQ 256
#define TV 256
#define DD 512
#define UU 128
#define NEGV (-1e9f)

__device__ __forceinline__ float fast_rcp(float x) {
    return __builtin_amdgcn_rcpf(x);   // v_rcp_f32
}
__device__ __forceinline__ float4 f4fma(float s, float4 v, float4 a) {
    a.x = fmaf(s, v.x, a.x); a.y = fmaf(s, v.y, a.y);
    a.z = fmaf(s, v.z, a.z); a.w = fmaf(s, v.w, a.w);
    return a;
}
__device__ __forceinline__ unsigned bf16rne(float x) {   // round-to-nearest-even bf16
    unsigned u = __float_as_uint(x);
    u += 0x7fffu + ((u >> 16) & 1u);
    return u >> 16;
}
__device__ __forceinline__ unsigned pack2bf(float lo, float hi) {
    return bf16rne(lo) | (bf16rne(hi) << 16);
}
__device__ __forceinline__ float4 bf4_to_f4(ushort4 u) {
    float4 r;
    r.x = __uint_as_float((unsigned)u.x << 16);
    r.y = __uint_as_float((unsigned)u.y << 16);
    r.z = __uint_as_float((unsigned)u.z << 16);
    r.w = __uint_as_float((unsigned)u.w << 16);
    return r;
}

// ---------------- kernel 1: projections (R18 body) + bf16 value emission ----------------
__global__ __launch_bounds__(256) void proj_kernel(
    const float* __restrict__ query, const float* __restrict__ value,
    const float* __restrict__ W1, const float* __restrict__ W2,
    float* __restrict__ eqp /* [B*TQ][U] = exp(2q) */,
    float* __restrict__ ekT /* [B][U][TV] = exp(2k) */,
    unsigned short* __restrict__ vbf /* [B*TV][D] bf16 value copy, or null */) {
    int bid = blockIdx.x;              // 0..255
    int which = bid >> 7;              // 0 = q, 1 = k
    int row0 = (bid & 127) * 8;
    const float* X = which ? value : query;
    const float* W = which ? W2 : W1;
    int tid = threadIdx.x;
    int ug = tid & 31;                 // u-group: u0 = ug*4
    int kc = tid >> 5;                 // K-eighth 0..7 (64 d each)
    int u0 = ug * 4;

    __shared__ float xs[8 * DD];       // 16 KB: 8 input rows
    __shared__ float part[7][8][UU];   // 28 KB: split-K partials

    {   // stage 8 rows via float4, coalesced
        const float4* src = (const float4*)(X + (size_t)row0 * DD);
        float4* dst = (float4*)xs;
        #pragma unroll
        for (int i = 0; i < 4; ++i) dst[tid + 256 * i] = src[tid + 256 * i];
    }
    __syncthreads();

    // one-time: k-proj blocks emit bf16 copy of their value rows (for attn phase B)
    if (which == 1 && vbf) {
        // thread tid converts 16 consecutive floats of xs (4096 total)
        int r = (tid * 16) >> 9, d = (tid * 16) & 511;
        const float4* s4 = (const float4*)xs + tid * 4;
        float4 f0 = s4[0], f1 = s4[1], f2 = s4[2], f3 = s4[3];
        uint4 o0 = make_uint4(pack2bf(f0.x, f0.y), pack2bf(f0.z, f0.w),
                              pack2bf(f1.x, f1.y), pack2bf(f1.z, f1.w));
        uint4 o1 = make_uint4(pack2bf(f2.x, f2.y), pack2bf(f2.z, f2.w),
                              pack2bf(f3.x, f3.y), pack2bf(f3.z, f3.w));
        uint4* dst = (uint4*)(vbf + (size_t)(row0 + r) * DD + d);
        dst[0] = o0; dst[1] = o1;
    }

    const float* Wb = W + (size_t)(kc * 64) * UU + u0;
    float4 acc0 = make_float4(0.f,0.f,0.f,0.f), acc1 = acc0, acc2 = acc0,
           acc3 = acc0, acc4 = acc0, acc5 = acc0, acc6 = acc0, acc7 = acc0;
    #pragma unroll 4
    for (int c = 0; c < 16; ++c) {     // 16 chunks x 4 d
        float4 x0 = ((const float4*)(xs + 0 * DD + kc * 64))[c];
        float4 x1 = ((const float4*)(xs + 1 * DD + kc * 64))[c];
        float4 x2 = ((const float4*)(xs + 2 * DD + kc * 64))[c];
        float4 x3 = ((const float4*)(xs + 3 * DD + kc * 64))[c];
        float4 x4 = ((const float4*)(xs + 4 * DD + kc * 64))[c];
        float4 x5 = ((const float4*)(xs + 5 * DD + kc * 64))[c];
        float4 x6 = ((const float4*)(xs + 6 * DD + kc * 64))[c];
        float4 x7 = ((const float4*)(xs + 7 * DD + kc * 64))[c];
        float4 w0 = *(const float4*)(Wb + (size_t)(c * 4 + 0) * UU);
        float4 w1 = *(const float4*)(Wb + (size_t)(c * 4 + 1) * UU);
        float4 w2 = *(const float4*)(Wb + (size_t)(c * 4 + 2) * UU);
        float4 w3 = *(const float4*)(Wb + (size_t)(c * 4 + 3) * UU);
        acc0 = f4fma(x0.x, w0, f4fma(x0.y, w1, f4fma(x0.z, w2, f4fma(x0.w, w3, acc0))));
        acc1 = f4fma(x1.x, w0, f4fma(x1.y, w1, f4fma(x1.z, w2, f4fma(x1.w, w3, acc1))));
        acc2 = f4fma(x2.x, w0, f4fma(x2.y, w1, f4fma(x2.z, w2, f4fma(x2.w, w3, acc2))));
        acc3 = f4fma(x3.x, w0, f4fma(x3.y, w1, f4fma(x3.z, w2, f4fma(x3.w, w3, acc3))));
        acc4 = f4fma(x4.x, w0, f4fma(x4.y, w1, f4fma(x4.z, w2, f4fma(x4.w, w3, acc4))));
        acc5 = f4fma(x5.x, w0, f4fma(x5.y, w1, f4fma(x5.z, w2, f4fma(x5.w, w3, acc5))));
        acc6 = f4fma(x6.x, w0, f4fma(x6.y, w1, f4fma(x6.z, w2, f4fma(x6.w, w3, acc6))));
        acc7 = f4fma(x7.x, w0, f4fma(x7.y, w1, f4fma(x7.z, w2, f4fma(x7.w, w3, acc7))));
    }
    __syncthreads();
    if (kc) {
        ((float4*)&part[kc - 1][0][0])[ug] = acc0;
        ((float4*)&part[kc - 1][1][0])[ug] = acc1;
        ((float4*)&part[kc - 1][2][0])[ug] = acc2;
        ((float4*)&part[kc - 1][3][0])[ug] = acc3;
        ((float4*)&part[kc - 1][4][0])[ug] = acc4;
        ((float4*)&part[kc - 1][5][0])[ug] = acc5;
        ((float4*)&part[kc - 1][6][0])[ug] = acc6;
        ((float4*)&part[kc - 1][7][0])[ug] = acc7;
    }
    __syncthreads();
    if (!kc) {
        #pragma unroll
        for (int j = 0; j < 7; ++j) {
            float4 p;
            p = ((float4*)&part[j][0][0])[ug]; acc0.x+=p.x; acc0.y+=p.y; acc0.z+=p.z; acc0.w+=p.w;
            p = ((float4*)&part[j][1][0])[ug]; acc1.x+=p.x; acc1.y+=p.y; acc1.z+=p.z; acc1.w+=p.w;
            p = ((float4*)&part[j][2][0])[ug]; acc2.x+=p.x; acc2.y+=p.y; acc2.z+=p.z; acc2.w+=p.w;
            p = ((float4*)&part[j][3][0])[ug]; acc3.x+=p.x; acc3.y+=p.y; acc3.z+=p.z; acc3.w+=p.w;
            p = ((float4*)&part[j][4][0])[ug]; acc4.x+=p.x; acc4.y+=p.y; acc4.z+=p.z; acc4.w+=p.w;
            p = ((float4*)&part[j][5][0])[ug]; acc5.x+=p.x; acc5.y+=p.y; acc5.z+=p.z; acc5.w+=p.w;
            p = ((float4*)&part[j][6][0])[ug]; acc6.x+=p.x; acc6.y+=p.y; acc6.z+=p.z; acc6.w+=p.w;
            p = ((float4*)&part[j][7][0])[ug]; acc7.x+=p.x; acc7.y+=p.y; acc7.z+=p.z; acc7.w+=p.w;
        }
        #define EXP4(A) A.x=__expf(2.f*A.x); A.y=__expf(2.f*A.y); A.z=__expf(2.f*A.z); A.w=__expf(2.f*A.w);
        EXP4(acc0) EXP4(acc1) EXP4(acc2) EXP4(acc3)
        EXP4(acc4) EXP4(acc5) EXP4(acc6) EXP4(acc7)
        if (which == 0) {
            float4* p = (float4*)(eqp + (size_t)row0 * UU + u0);
            p[0*(UU/4)] = acc0; p[1*(UU/4)] = acc1; p[2*(UU/4)] = acc2; p[3*(UU/4)] = acc3;
            p[4*(UU/4)] = acc4; p[5*(UU/4)] = acc5; p[6*(UU/4)] = acc6; p[7*(UU/4)] = acc7;
        } else {
            int b = row0 >> 8, v0 = row0 & 255;
            #define KSTORE(J, CX) { \
                float4 lo = make_float4(acc0.CX, acc1.CX, acc2.CX, acc3.CX); \
                float4 hi = make_float4(acc4.CX, acc5.CX, acc6.CX, acc7.CX); \
                float* dst = ekT + ((size_t)(b * UU) + u0 + J) * TV + v0;    \
                *(float4*)dst = lo; *(float4*)(dst + 4) = hi; }
            KSTORE(0, x) KSTORE(1, y) KSTORE(2, z) KSTORE(3, w)
        }
    }
}

// ---------------- kernel 2: FUSED attn; no-max softmax, ballot flags, bf16 value ----------------
template<bool BF16V>
__global__ __launch_bounds__(1024) void attn_kernel(
    const float* __restrict__ eqp, const float* __restrict__ ekT,
    const float* __restrict__ scale, const unsigned char* __restrict__ m,
    const float* __restrict__ value, const unsigned short* __restrict__ vbf,
    float* __restrict__ ctx, float* __restrict__ weights) {
    int blk = blockIdx.x;              // 0..255
    int b = blk >> 6;
    int q0 = (blk & 63) * 4;
    int tid = threadIdx.x;             // 0..1023
    int lane = tid & 63;

    __shared__ float eq4[4][UU];       // 2 KB
    __shared__ float sc2[UU];          // 512 B
    __shared__ union {                 // 56 KB (phases sync-separated)
        float pbA[8][4][TV];           // phase A partials (32 KB)
        float4 pbB[7][4][128];         // phase B flat partials (56 KB)
    } un;
    __shared__ float sv[4][TV];        // 4 KB
    __shared__ float redS[4][4];

    // mask layout flags via per-wave ballot over the first 1024 bytes
    // (safe in every layout: u8->1024B, i32/f32->4096B buffers)
    bool fF, fB;
    {
        bool aF = false, aB = false;
        #pragma unroll
        for (int i = 0; i < 4; ++i) {
            uchar4 c4 = ((const uchar4*)m)[lane * 4 + i];
            aF |= (c4.w == 0x3f);                     // float32 1.0f tail byte
            aB |= ((c4.y | c4.z | c4.w) != 0);        // off-word nonzero -> u8
        }
        fF = (__ballot(aF) != 0ull);
        fB = (__ballot(aB) != 0ull);
    }
    if (tid < 128) {
        ((float4*)eq4)[tid] = ((const float4*)(eqp + (size_t)(b * TQ + q0) * UU))[tid];
    } else if (tid < 160) {
        float4 s = ((const float4*)scale)[tid - 128];
        ((float4*)sc2)[tid - 128] = make_float4(-2.f*s.x, -2.f*s.y, -2.f*s.z, -2.f*s.w);
    }
    __syncthreads();

    // ---- phase A: scores ----
    {
        int vp = tid & 127;
        int h = tid >> 7;
        const float2* kb2 = (const float2*)(ekT + ((size_t)b * UU + h * 16) * TV) + vp;
        float ax0=0.f, ay0=0.f, ax1=0.f, ay1=0.f;
        float ax2=0.f, ay2=0.f, ax3=0.f, ay3=0.f;
        #pragma unroll
        for (int c = 0; c < 4; ++c) {
            float4 e0 = ((const float4*)&eq4[0][0])[h * 4 + c];
            float4 e1 = ((const float4*)&eq4[1][0])[h * 4 + c];
            float4 e2 = ((const float4*)&eq4[2][0])[h * 4 + c];
            float4 e3 = ((const float4*)&eq4[3][0])[h * 4 + c];
            float4 sc = ((const float4*)sc2)[h * 4 + c];
            #define ASTEP(J, CX) { \
                float2 ek = kb2[(size_t)(c * 4 + J) * (TV / 2)]; \
                ax0 = fmaf(sc.CX, fast_rcp(fmaf(e0.CX, ek.x, 1.f)), ax0); \
                ay0 = fmaf(sc.CX, fast_rcp(fmaf(e0.CX, ek.y, 1.f)), ay0); \
                ax1 = fmaf(sc.CX, fast_rcp(fmaf(e1.CX, ek.x, 1.f)), ax1); \
                ay1 = fmaf(sc.CX, fast_rcp(fmaf(e1.CX, ek.y, 1.f)), ay1); \
                ax2 = fmaf(sc.CX, fast_rcp(fmaf(e2.CX, ek.x, 1.f)), ax2); \
                ay2 = fmaf(sc.CX, fast_rcp(fmaf(e2.CX, ek.y, 1.f)), ay2); \
                ax3 = fmaf(sc.CX, fast_rcp(fmaf(e3.CX, ek.x, 1.f)), ax3); \
                ay3 = fmaf(sc.CX, fast_rcp(fmaf(e3.CX, ek.y, 1.f)), ay3); }
            ASTEP(0, x) ASTEP(1, y) ASTEP(2, z) ASTEP(3, w)
        }
        ((float2*)&un.pbA[h][0][0])[vp] = make_float2(ax0, ay0);
        ((float2*)&un.pbA[h][1][0])[vp] = make_float2(ax1, ay1);
        ((float2*)&un.pbA[h][2][0])[vp] = make_float2(ax2, ay2);
        ((float2*)&un.pbA[h][3][0])[vp] = make_float2(ax3, ay3);
        __syncthreads();
        if (h < 4) {
            float2 s = make_float2(0.f, 0.f);
            #pragma unroll
            for (int g = 0; g < 8; ++g) {
                float2 p = ((float2*)&un.pbA[g][h][0])[vp];
                s.x += p.x; s.y += p.y;
            }
            ((float2*)&sv[h][0])[vp] = s;
        }
        __syncthreads();
    }

    // ---- masked softmax, NO max pass (|s|<~30 bounded; masked -> exp(-1e9)=0) ----
    {
        int v = tid & 255;
        float e0, e1, e2, e3;
        if (tid < 256) {
            float mk;
            {
                int idx = b * TV + v;
                bool ok;
                if (fF)      ok = (m[4 * idx + 3] != 0);
                else if (fB) ok = (m[idx] != 0);
                else         ok = (m[4 * idx] != 0);  // int32 LSB
                mk = ok ? __builtin_inff() : NEGV;
            }
            e0 = __expf(fminf(sv[0][v], mk));
            e1 = __expf(fminf(sv[1][v], mk));
            e2 = __expf(fminf(sv[2][v], mk));
            e3 = __expf(fminf(sv[3][v], mk));
            float t0 = e0, t1 = e1, t2 = e2, t3 = e3;
            #pragma unroll
            for (int off = 32; off >= 1; off >>= 1) {
                t0 += __shfl_xor(t0, off); t1 += __shfl_xor(t1, off);
                t2 += __shfl_xor(t2, off); t3 += __shfl_xor(t3, off);
            }
            int wid = tid >> 6;
            if (lane == 0) {
                redS[0][wid] = t0; redS[1][wid] = t1;
                redS[2][wid] = t2; redS[3][wid] = t3;
            }
        }
        __syncthreads();
        if (tid < 256) {
            float r0 = fast_rcp((redS[0][0] + redS[0][1]) + (redS[0][2] + redS[0][3]));
            float r1 = fast_rcp((redS[1][0] + redS[1][1]) + (redS[1][2] + redS[1][3]));
            float r2 = fast_rcp((redS[2][0] + redS[2][1]) + (redS[2][2] + redS[2][3]));
            float r3 = fast_rcp((redS[3][0] + redS[3][1]) + (redS[3][2] + redS[3][3]));
            float w0 = e0 * r0, w1 = e1 * r1, w2 = e2 * r2, w3 = e3 * r3;
            float* wp = weights + (size_t)(b * TQ + q0) * TV + v;
            wp[0 * TV] = w0; wp[1 * TV] = w1; wp[2 * TV] = w2; wp[3 * TV] = w3;
            sv[0][v] = w0; sv[1][v] = w1; sv[2][v] = w2; sv[3][v] = w3;
        }
        __syncthreads();
    }

    // ---- phase B: flat combine; value as bf16 (half traffic) or fp32 ----
    {
        int df = tid & 127;
        int vh = tid >> 7;
        float4 c0 = make_float4(0.f,0.f,0.f,0.f), c1 = c0, c2 = c0, c3 = c0;
        const float4* vb4f = (const float4*)(value + ((size_t)b * TV + vh * 32) * DD) + df;
        const ushort4* vb4h = BF16V
            ? (const ushort4*)(vbf + ((size_t)b * TV + vh * 32) * DD) + df : nullptr;
        #pragma unroll
        for (int vc = 0; vc < 8; ++vc) {
            float4 w0 = ((const float4*)&sv[0][0])[vh * 8 + vc];
            float4 w1 = ((const float4*)&sv[1][0])[vh * 8 + vc];
            float4 w2 = ((const float4*)&sv[2][0])[vh * 8 + vc];
            float4 w3 = ((const float4*)&sv[3][0])[vh * 8 + vc];
            #define BSTEP(J, CX) { \
                float4 vv = BF16V ? bf4_to_f4(vb4h[(size_t)(vc * 4 + J) * (DD / 4)]) \
                                  : vb4f[(size_t)(vc * 4 + J) * (DD / 4)]; \
                c0 = f4fma(w0.CX, vv, c0); c1 = f4fma(w1.CX, vv, c1); \
                c2 = f4fma(w2.CX, vv, c2); c3 = f4fma(w3.CX, vv, c3); }
            BSTEP(0, x) BSTEP(1, y) BSTEP(2, z) BSTEP(3, w)
        }
        if (vh > 0) {
            un.pbB[vh-1][0][df] = c0; un.pbB[vh-1][1][df] = c1;
            un.pbB[vh-1][2][df] = c2; un.pbB[vh-1][3][df] = c3;
        }
        __syncthreads();
        if (vh == 0) {
            #pragma unroll
            for (int j = 0; j < 7; ++j) {
                float4 p;
                p = un.pbB[j][0][df]; c0.x+=p.x; c0.y+=p.y; c0.z+=p.z; c0.w+=p.w;
                p = un.pbB[j][1][df]; c1.x+=p.x; c1.y+=p.y; c1.z+=p.z; c1.w+=p.w;
                p = un.pbB[j][2][df]; c2.x+=p.x; c2.y+=p.y; c2.z+=p.z; c2.w+=p.w;
                p = un.pbB[j][3][df]; c3.x+=p.x; c3.y+=p.y; c3.z+=p.z; c3.w+=p.w;
            }
            ((float4*)(ctx + (size_t)(b * TQ + q0 + 0) * DD))[df] = c0;
            ((float4*)(ctx + (size_t)(b * TQ + q0 + 1) * DD))[df] = c1;
            ((float4*)(ctx + (size_t)(b * TQ + q0 + 2) * DD))[df] = c2;
            ((float4*)(ctx + (size_t)(b * TQ + q0 + 3) * DD))[df] = c3;
        }
    }
}

extern "C" void kernel_launch(void* const* d_in, const int* in_sizes, int n_in,
                              void* d_out, int out_size, void* d_ws, size_t ws_size,
                              hipStream_t stream) {
    const float* query = (const float*)d_in[0];
    const float* value = (const float*)d_in[1];
    const unsigned char* mask = (const unsigned char*)d_in[2];
    const float* W1 = (const float*)d_in[3];
    const float* W2 = (const float*)d_in[4];
    const float* scale = (const float*)d_in[5];

    float* ctx = (float*)d_out;                              // [B,TQ,D]
    float* weights = (float*)d_out + (size_t)BB * TQ * DD;   // [B,TQ,TV]

    float* eqp = (float*)d_ws;                               // 512 KB
    float* ekT = eqp + (size_t)BB * TQ * UU;                 // 512 KB
    unsigned short* vbf = (unsigned short*)(ekT + (size_t)BB * UU * TV); // 1 MB

    size_t need = ((size_t)BB * TQ * UU + (size_t)BB * UU * TV) * sizeof(float)
                + (size_t)BB * TV * DD * sizeof(unsigned short);   // 2 MB
    bool usebf = (ws_size >= need);

    proj_kernel<<<256, 256, 0, stream>>>(query, value, W1, W2, eqp, ekT,
                                         usebf ? vbf : nullptr);
    if (usebf)
        attn_kernel<true><<<256, 1024, 0, stream>>>(eqp, ekT, scale, mask,
                                                    value, vbf, ctx, weights);
    else
        attn_kernel<false><<<256, 1024, 0, stream>>>(eqp, ekT, scale, mask,
                                                     value, nullptr, ctx, weights);
}

// Round 21
// 26.775 us; speedup vs baseline: 1.3211x; 1.1066x over previous
//
#include <hip/hip_runtime.h>
#include <math.h>

#define BB 4
#define TQ 256
#define TV 256
#define DD 512
#define UU 128
#define NEGV (-1e9f)

__device__ __forceinline__ float fast_rcp(float x) {
    return __builtin_amdgcn_rcpf(x);   // v_rcp_f32
}
__device__ __forceinline__ float4 f4fma(float s, float4 v, float4 a) {
    a.x = fmaf(s, v.x, a.x); a.y = fmaf(s, v.y, a.y);
    a.z = fmaf(s, v.z, a.z); a.w = fmaf(s, v.w, a.w);
    return a;
}

// ---------------- kernel 1: projections, register-tiled (R18 body, unchanged) ----------------
__global__ __launch_bounds__(256) void proj_kernel(
    const float* __restrict__ query, const float* __restrict__ value,
    const float* __restrict__ W1, const float* __restrict__ W2,
    float* __restrict__ eqp /* [B*TQ][U] = exp(2q) */,
    float* __restrict__ ekT /* [B][U][TV] = exp(2k) */) {
    int bid = blockIdx.x;              // 0..255
    int which = bid >> 7;              // 0 = q, 1 = k
    int row0 = (bid & 127) * 8;
    const float* X = which ? value : query;
    const float* W = which ? W2 : W1;
    int tid = threadIdx.x;
    int ug = tid & 31;                 // u-group: u0 = ug*4
    int kc = tid >> 5;                 // K-eighth 0..7 (64 d each)
    int u0 = ug * 4;

    __shared__ float xs[8 * DD];       // 16 KB: 8 input rows
    __shared__ float part[7][8][UU];   // 28 KB: split-K partials

    {   // stage 8 rows via float4, coalesced
        const float4* src = (const float4*)(X + (size_t)row0 * DD);
        float4* dst = (float4*)xs;
        #pragma unroll
        for (int i = 0; i < 4; ++i) dst[tid + 256 * i] = src[tid + 256 * i];
    }
    __syncthreads();

    const float* Wb = W + (size_t)(kc * 64) * UU + u0;
    float4 acc0 = make_float4(0.f,0.f,0.f,0.f), acc1 = acc0, acc2 = acc0,
           acc3 = acc0, acc4 = acc0, acc5 = acc0, acc6 = acc0, acc7 = acc0;
    #pragma unroll 4
    for (int c = 0; c < 16; ++c) {     // 16 chunks x 4 d
        float4 x0 = ((const float4*)(xs + 0 * DD + kc * 64))[c];
        float4 x1 = ((const float4*)(xs + 1 * DD + kc * 64))[c];
        float4 x2 = ((const float4*)(xs + 2 * DD + kc * 64))[c];
        float4 x3 = ((const float4*)(xs + 3 * DD + kc * 64))[c];
        float4 x4 = ((const float4*)(xs + 4 * DD + kc * 64))[c];
        float4 x5 = ((const float4*)(xs + 5 * DD + kc * 64))[c];
        float4 x6 = ((const float4*)(xs + 6 * DD + kc * 64))[c];
        float4 x7 = ((const float4*)(xs + 7 * DD + kc * 64))[c];
        float4 w0 = *(const float4*)(Wb + (size_t)(c * 4 + 0) * UU);
        float4 w1 = *(const float4*)(Wb + (size_t)(c * 4 + 1) * UU);
        float4 w2 = *(const float4*)(Wb + (size_t)(c * 4 + 2) * UU);
        float4 w3 = *(const float4*)(Wb + (size_t)(c * 4 + 3) * UU);
        acc0 = f4fma(x0.x, w0, f4fma(x0.y, w1, f4fma(x0.z, w2, f4fma(x0.w, w3, acc0))));
        acc1 = f4fma(x1.x, w0, f4fma(x1.y, w1, f4fma(x1.z, w2, f4fma(x1.w, w3, acc1))));
        acc2 = f4fma(x2.x, w0, f4fma(x2.y, w1, f4fma(x2.z, w2, f4fma(x2.w, w3, acc2))));
        acc3 = f4fma(x3.x, w0, f4fma(x3.y, w1, f4fma(x3.z, w2, f4fma(x3.w, w3, acc3))));
        acc4 = f4fma(x4.x, w0, f4fma(x4.y, w1, f4fma(x4.z, w2, f4fma(x4.w, w3, acc4))));
        acc5 = f4fma(x5.x, w0, f4fma(x5.y, w1, f4fma(x5.z, w2, f4fma(x5.w, w3, acc5))));
        acc6 = f4fma(x6.x, w0, f4fma(x6.y, w1, f4fma(x6.z, w2, f4fma(x6.w, w3, acc6))));
        acc7 = f4fma(x7.x, w0, f4fma(x7.y, w1, f4fma(x7.z, w2, f4fma(x7.w, w3, acc7))));
    }
    __syncthreads();
    if (kc) {
        ((float4*)&part[kc - 1][0][0])[ug] = acc0;
        ((float4*)&part[kc - 1][1][0])[ug] = acc1;
        ((float4*)&part[kc - 1][2][0])[ug] = acc2;
        ((float4*)&part[kc - 1][3][0])[ug] = acc3;
        ((float4*)&part[kc - 1][4][0])[ug] = acc4;
        ((float4*)&part[kc - 1][5][0])[ug] = acc5;
        ((float4*)&part[kc - 1][6][0])[ug] = acc6;
        ((float4*)&part[kc - 1][7][0])[ug] = acc7;
    }
    __syncthreads();
    if (!kc) {
        #pragma unroll
        for (int j = 0; j < 7; ++j) {
            float4 p;
            p = ((float4*)&part[j][0][0])[ug]; acc0.x+=p.x; acc0.y+=p.y; acc0.z+=p.z; acc0.w+=p.w;
            p = ((float4*)&part[j][1][0])[ug]; acc1.x+=p.x; acc1.y+=p.y; acc1.z+=p.z; acc1.w+=p.w;
            p = ((float4*)&part[j][2][0])[ug]; acc2.x+=p.x; acc2.y+=p.y; acc2.z+=p.z; acc2.w+=p.w;
            p = ((float4*)&part[j][3][0])[ug]; acc3.x+=p.x; acc3.y+=p.y; acc3.z+=p.z; acc3.w+=p.w;
            p = ((float4*)&part[j][4][0])[ug]; acc4.x+=p.x; acc4.y+=p.y; acc4.z+=p.z; acc4.w+=p.w;
            p = ((float4*)&part[j][5][0])[ug]; acc5.x+=p.x; acc5.y+=p.y; acc5.z+=p.z; acc5.w+=p.w;
            p = ((float4*)&part[j][6][0])[ug]; acc6.x+=p.x; acc6.y+=p.y; acc6.z+=p.z; acc6.w+=p.w;
            p = ((float4*)&part[j][7][0])[ug]; acc7.x+=p.x; acc7.y+=p.y; acc7.z+=p.z; acc7.w+=p.w;
        }
        #define EXP4(A) A.x=__expf(2.f*A.x); A.y=__expf(2.f*A.y); A.z=__expf(2.f*A.z); A.w=__expf(2.f*A.w);
        EXP4(acc0) EXP4(acc1) EXP4(acc2) EXP4(acc3)
        EXP4(acc4) EXP4(acc5) EXP4(acc6) EXP4(acc7)
        if (which == 0) {
            float4* p = (float4*)(eqp + (size_t)row0 * UU + u0);
            p[0*(UU/4)] = acc0; p[1*(UU/4)] = acc1; p[2*(UU/4)] = acc2; p[3*(UU/4)] = acc3;
            p[4*(UU/4)] = acc4; p[5*(UU/4)] = acc5; p[6*(UU/4)] = acc6; p[7*(UU/4)] = acc7;
        } else {
            int b = row0 >> 8, v0 = row0 & 255;
            #define KSTORE(J, CX) { \
                float4 lo = make_float4(acc0.CX, acc1.CX, acc2.CX, acc3.CX); \
                float4 hi = make_float4(acc4.CX, acc5.CX, acc6.CX, acc7.CX); \
                float* dst = ekT + ((size_t)(b * UU) + u0 + J) * TV + v0;    \
                *(float4*)dst = lo; *(float4*)(dst + 4) = hi; }
            KSTORE(0, x) KSTORE(1, y) KSTORE(2, z) KSTORE(3, w)
        }
    }
}

// ---------------- kernel 2: FUSED attn (R18 body + no-max softmax + ballot flags) ----------------
__global__ __launch_bounds__(1024) void attn_kernel(
    const float* __restrict__ eqp, const float* __restrict__ ekT,
    const float* __restrict__ scale, const unsigned char* __restrict__ m,
    const float* __restrict__ value,
    float* __restrict__ ctx, float* __restrict__ weights) {
    int blk = blockIdx.x;              // 0..255
    int b = blk >> 6;
    int q0 = (blk & 63) * 4;
    int tid = threadIdx.x;             // 0..1023
    int lane = tid & 63;

    __shared__ float eq4[4][UU];       // 2 KB
    __shared__ float sc2[UU];          // 512 B
    __shared__ union {                 // 56 KB (phases sync-separated)
        float pbA[8][4][TV];           // phase A partials (32 KB)
        float4 pbB[7][4][128];         // phase B flat partials (56 KB)
    } un;
    __shared__ float sv[4][TV];        // 4 KB
    __shared__ float redS[4][4];

    // mask layout flags via per-wave ballot over the first 1024 bytes
    // (safe in every layout: u8->1024B, i32/f32->4096B buffers); pure-removal
    // replacement for the LDS flags + barrier of R18.
    bool fF, fB;
    {
        bool aF = false, aB = false;
        #pragma unroll
        for (int i = 0; i < 4; ++i) {
            uchar4 c4 = ((const uchar4*)m)[lane * 4 + i];
            aF |= (c4.w == 0x3f);                     // float32 1.0f tail byte
            aB |= ((c4.y | c4.z | c4.w) != 0);        // off-word nonzero -> u8
        }
        fF = (__ballot(aF) != 0ull);
        fB = (__ballot(aB) != 0ull);
    }
    if (tid < 128) {
        ((float4*)eq4)[tid] = ((const float4*)(eqp + (size_t)(b * TQ + q0) * UU))[tid];
    } else if (tid < 160) {
        float4 s = ((const float4*)scale)[tid - 128];
        ((float4*)sc2)[tid - 128] = make_float4(-2.f*s.x, -2.f*s.y, -2.f*s.z, -2.f*s.w);
    }
    __syncthreads();

    // ---- phase A: scores ----
    {
        int vp = tid & 127;
        int h = tid >> 7;
        const float2* kb2 = (const float2*)(ekT + ((size_t)b * UU + h * 16) * TV) + vp;
        float ax0=0.f, ay0=0.f, ax1=0.f, ay1=0.f;
        float ax2=0.f, ay2=0.f, ax3=0.f, ay3=0.f;
        #pragma unroll
        for (int c = 0; c < 4; ++c) {
            float4 e0 = ((const float4*)&eq4[0][0])[h * 4 + c];
            float4 e1 = ((const float4*)&eq4[1][0])[h * 4 + c];
            float4 e2 = ((const float4*)&eq4[2][0])[h * 4 + c];
            float4 e3 = ((const float4*)&eq4[3][0])[h * 4 + c];
            float4 sc = ((const float4*)sc2)[h * 4 + c];
            #define ASTEP(J, CX) { \
                float2 ek = kb2[(size_t)(c * 4 + J) * (TV / 2)]; \
                ax0 = fmaf(sc.CX, fast_rcp(fmaf(e0.CX, ek.x, 1.f)), ax0); \
                ay0 = fmaf(sc.CX, fast_rcp(fmaf(e0.CX, ek.y, 1.f)), ay0); \
                ax1 = fmaf(sc.CX, fast_rcp(fmaf(e1.CX, ek.x, 1.f)), ax1); \
                ay1 = fmaf(sc.CX, fast_rcp(fmaf(e1.CX, ek.y, 1.f)), ay1); \
                ax2 = fmaf(sc.CX, fast_rcp(fmaf(e2.CX, ek.x, 1.f)), ax2); \
                ay2 = fmaf(sc.CX, fast_rcp(fmaf(e2.CX, ek.y, 1.f)), ay2); \
                ax3 = fmaf(sc.CX, fast_rcp(fmaf(e3.CX, ek.x, 1.f)), ax3); \
                ay3 = fmaf(sc.CX, fast_rcp(fmaf(e3.CX, ek.y, 1.f)), ay3); }
            ASTEP(0, x) ASTEP(1, y) ASTEP(2, z) ASTEP(3, w)
        }
        ((float2*)&un.pbA[h][0][0])[vp] = make_float2(ax0, ay0);
        ((float2*)&un.pbA[h][1][0])[vp] = make_float2(ax1, ay1);
        ((float2*)&un.pbA[h][2][0])[vp] = make_float2(ax2, ay2);
        ((float2*)&un.pbA[h][3][0])[vp] = make_float2(ax3, ay3);
        __syncthreads();
        if (h < 4) {
            float2 s = make_float2(0.f, 0.f);
            #pragma unroll
            for (int g = 0; g < 8; ++g) {
                float2 p = ((float2*)&un.pbA[g][h][0])[vp];
                s.x += p.x; s.y += p.y;
            }
            ((float2*)&sv[h][0])[vp] = s;
        }
        __syncthreads();
    }

    // ---- masked softmax, NO max pass (|s'| <= 2*sum|scale| << 88; masked -> exp(-1e9)=0) ----
    {
        int v = tid & 255;
        float e0, e1, e2, e3;
        if (tid < 256) {
            float mk;
            {
                int idx = b * TV + v;
                bool ok;
                if (fF)      ok = (m[4 * idx + 3] != 0);
                else if (fB) ok = (m[idx] != 0);
                else         ok = (m[4 * idx] != 0);  // int32 LSB
                mk = ok ? __builtin_inff() : NEGV;
            }
            e0 = __expf(fminf(sv[0][v], mk));
            e1 = __expf(fminf(sv[1][v], mk));
            e2 = __expf(fminf(sv[2][v], mk));
            e3 = __expf(fminf(sv[3][v], mk));
            float t0 = e0, t1 = e1, t2 = e2, t3 = e3;
            #pragma unroll
            for (int off = 32; off >= 1; off >>= 1) {
                t0 += __shfl_xor(t0, off); t1 += __shfl_xor(t1, off);
                t2 += __shfl_xor(t2, off); t3 += __shfl_xor(t3, off);
            }
            int wid = tid >> 6;
            if (lane == 0) {
                redS[0][wid] = t0; redS[1][wid] = t1;
                redS[2][wid] = t2; redS[3][wid] = t3;
            }
        }
        __syncthreads();
        if (tid < 256) {
            float r0 = fast_rcp((redS[0][0] + redS[0][1]) + (redS[0][2] + redS[0][3]));
            float r1 = fast_rcp((redS[1][0] + redS[1][1]) + (redS[1][2] + redS[1][3]));
            float r2 = fast_rcp((redS[2][0] + redS[2][1]) + (redS[2][2] + redS[2][3]));
            float r3 = fast_rcp((redS[3][0] + redS[3][1]) + (redS[3][2] + redS[3][3]));
            float w0 = e0 * r0, w1 = e1 * r1, w2 = e2 * r2, w3 = e3 * r3;
            float* wp = weights + (size_t)(b * TQ + q0) * TV + v;
            wp[0 * TV] = w0; wp[1 * TV] = w1; wp[2 * TV] = w2; wp[3 * TV] = w3;
            sv[0][v] = w0; sv[1][v] = w1; sv[2][v] = w2; sv[3][v] = w3;
        }
        __syncthreads();
    }

    // ---- phase B: flat combine (vh 1..7 write pbB; 1 barrier; vh 0 reduces) ----
    {
        int df = tid & 127;
        int vh = tid >> 7;
        const float4* vb4 = (const float4*)(value + ((size_t)b * TV + vh * 32) * DD) + df;
        float4 c0 = make_float4(0.f,0.f,0.f,0.f), c1 = c0, c2 = c0, c3 = c0;
        #pragma unroll
        for (int vc = 0; vc < 8; ++vc) {
            float4 w0 = ((const float4*)&sv[0][0])[vh * 8 + vc];
            float4 w1 = ((const float4*)&sv[1][0])[vh * 8 + vc];
            float4 w2 = ((const float4*)&sv[2][0])[vh * 8 + vc];
            float4 w3 = ((const float4*)&sv[3][0])[vh * 8 + vc];
            #define BSTEP(J, CX) { \
                float4 vv = vb4[(size_t)(vc * 4 + J) * (DD / 4)]; \
                c0 = f4fma(w0.CX, vv, c0); c1 = f4fma(w1.CX, vv, c1); \
                c2 = f4fma(w2.CX, vv, c2); c3 = f4fma(w3.CX, vv, c3); }
            BSTEP(0, x) BSTEP(1, y) BSTEP(2, z) BSTEP(3, w)
        }
        if (vh > 0) {
            un.pbB[vh-1][0][df] = c0; un.pbB[vh-1][1][df] = c1;
            un.pbB[vh-1][2][df] = c2; un.pbB[vh-1][3][df] = c3;
        }
        __syncthreads();
        if (vh == 0) {
            #pragma unroll
            for (int j = 0; j < 7; ++j) {
                float4 p;
                p = un.pbB[j][0][df]; c0.x+=p.x; c0.y+=p.y; c0.z+=p.z; c0.w+=p.w;
                p = un.pbB[j][1][df]; c1.x+=p.x; c1.y+=p.y; c1.z+=p.z; c1.w+=p.w;
                p = un.pbB[j][2][df]; c2.x+=p.x; c2.y+=p.y; c2.z+=p.z; c2.w+=p.w;
                p = un.pbB[j][3][df]; c3.x+=p.x; c3.y+=p.y; c3.z+=p.z; c3.w+=p.w;
            }
            ((float4*)(ctx + (size_t)(b * TQ + q0 + 0) * DD))[df] = c0;
            ((float4*)(ctx + (size_t)(b * TQ + q0 + 1) * DD))[df] = c1;
            ((float4*)(ctx + (size_t)(b * TQ + q0 + 2) * DD))[df] = c2;
            ((float4*)(ctx + (size_t)(b * TQ + q0 + 3) * DD))[df] = c3;
        }
    }
}

extern "C" void kernel_launch(void* const* d_in, const int* in_sizes, int n_in,
                              void* d_out, int out_size, void* d_ws, size_t ws_size,
                              hipStream_t stream) {
    const float* query = (const float*)d_in[0];
    const float* value = (const float*)d_in[1];
    const unsigned char* mask = (const unsigned char*)d_in[2];
    const float* W1 = (const float*)d_in[3];
    const float* W2 = (const float*)d_in[4];
    const float* scale = (const float*)d_in[5];

    float* ctx = (float*)d_out;                              // [B,TQ,D]
    float* weights = (float*)d_out + (size_t)BB * TQ * DD;   // [B,TQ,TV]

    float* eqp = (float*)d_ws;                               // 512 KB
    float* ekT = eqp + (size_t)BB * TQ * UU;                 // 512 KB

    proj_kernel<<<256, 256, 0, stream>>>(query, value, W1, W2, eqp, ekT);
    attn_kernel<<<256, 1024, 0, stream>>>(eqp, ekT, scale, mask, value, ctx, weights);
}

// Round 22
// 25.845 us; speedup vs baseline: 1.3686x; 1.0360x over previous
//
#include <hip/hip_runtime.h>
#include <math.h>

#define BB 4
#define TQ 256
#define TV 256
#define DD 512
#define UU 128
#define NEGV (-1e9f)

__device__ __forceinline__ float fast_rcp(float x) {
    return __builtin_amdgcn_rcpf(x);   // v_rcp_f32
}
__device__ __forceinline__ float4 f4fma(float s, float4 v, float4 a) {
    a.x = fmaf(s, v.x, a.x); a.y = fmaf(s, v.y, a.y);
    a.z = fmaf(s, v.z, a.z); a.w = fmaf(s, v.w, a.w);
    return a;
}

// ---------------- kernel 1: projections, register-tiled ----------------
// 256 blocks x 256 thr; blocks 0..127 q-proj, 128..255 k-proj; 8 rows/block.
// Eq = exp(2*(query@W1)), EkT = exp(2*(value@W2)) transposed [B][U][TV].
// tanh(q+k) = 1 - 2/(1 + Eq*Ek); the +sum(scale) constant is softmax-shift-
// invariant (masked entries stay -1e9), so scores reduce to rcp+fma only.
__global__ __launch_bounds__(256) void proj_kernel(
    const float* __restrict__ query, const float* __restrict__ value,
    const float* __restrict__ W1, const float* __restrict__ W2,
    float* __restrict__ eqp /* [B*TQ][U] = exp(2q) */,
    float* __restrict__ ekT /* [B][U][TV] = exp(2k) */) {
    int bid = blockIdx.x;              // 0..255
    int which = bid >> 7;              // 0 = q, 1 = k
    int row0 = (bid & 127) * 8;
    const float* X = which ? value : query;
    const float* W = which ? W2 : W1;
    int tid = threadIdx.x;
    int ug = tid & 31;                 // u-group: u0 = ug*4
    int kc = tid >> 5;                 // K-eighth 0..7 (64 d each)
    int u0 = ug * 4;

    __shared__ float xs[8 * DD];       // 16 KB: 8 input rows
    __shared__ float part[7][8][UU];   // 28 KB: split-K partials

    {   // stage 8 rows via float4, coalesced
        const float4* src = (const float4*)(X + (size_t)row0 * DD);
        float4* dst = (float4*)xs;
        #pragma unroll
        for (int i = 0; i < 4; ++i) dst[tid + 256 * i] = src[tid + 256 * i];
    }
    __syncthreads();

    const float* Wb = W + (size_t)(kc * 64) * UU + u0;
    float4 acc0 = make_float4(0.f,0.f,0.f,0.f), acc1 = acc0, acc2 = acc0,
           acc3 = acc0, acc4 = acc0, acc5 = acc0, acc6 = acc0, acc7 = acc0;
    #pragma unroll 4
    for (int c = 0; c < 16; ++c) {     // 16 chunks x 4 d
        float4 x0 = ((const float4*)(xs + 0 * DD + kc * 64))[c];
        float4 x1 = ((const float4*)(xs + 1 * DD + kc * 64))[c];
        float4 x2 = ((const float4*)(xs + 2 * DD + kc * 64))[c];
        float4 x3 = ((const float4*)(xs + 3 * DD + kc * 64))[c];
        float4 x4 = ((const float4*)(xs + 4 * DD + kc * 64))[c];
        float4 x5 = ((const float4*)(xs + 5 * DD + kc * 64))[c];
        float4 x6 = ((const float4*)(xs + 6 * DD + kc * 64))[c];
        float4 x7 = ((const float4*)(xs + 7 * DD + kc * 64))[c];
        float4 w0 = *(const float4*)(Wb + (size_t)(c * 4 + 0) * UU);
        float4 w1 = *(const float4*)(Wb + (size_t)(c * 4 + 1) * UU);
        float4 w2 = *(const float4*)(Wb + (size_t)(c * 4 + 2) * UU);
        float4 w3 = *(const float4*)(Wb + (size_t)(c * 4 + 3) * UU);
        acc0 = f4fma(x0.x, w0, f4fma(x0.y, w1, f4fma(x0.z, w2, f4fma(x0.w, w3, acc0))));
        acc1 = f4fma(x1.x, w0, f4fma(x1.y, w1, f4fma(x1.z, w2, f4fma(x1.w, w3, acc1))));
        acc2 = f4fma(x2.x, w0, f4fma(x2.y, w1, f4fma(x2.z, w2, f4fma(x2.w, w3, acc2))));
        acc3 = f4fma(x3.x, w0, f4fma(x3.y, w1, f4fma(x3.z, w2, f4fma(x3.w, w3, acc3))));
        acc4 = f4fma(x4.x, w0, f4fma(x4.y, w1, f4fma(x4.z, w2, f4fma(x4.w, w3, acc4))));
        acc5 = f4fma(x5.x, w0, f4fma(x5.y, w1, f4fma(x5.z, w2, f4fma(x5.w, w3, acc5))));
        acc6 = f4fma(x6.x, w0, f4fma(x6.y, w1, f4fma(x6.z, w2, f4fma(x6.w, w3, acc6))));
        acc7 = f4fma(x7.x, w0, f4fma(x7.y, w1, f4fma(x7.z, w2, f4fma(x7.w, w3, acc7))));
    }
    __syncthreads();
    if (kc) {
        ((float4*)&part[kc - 1][0][0])[ug] = acc0;
        ((float4*)&part[kc - 1][1][0])[ug] = acc1;
        ((float4*)&part[kc - 1][2][0])[ug] = acc2;
        ((float4*)&part[kc - 1][3][0])[ug] = acc3;
        ((float4*)&part[kc - 1][4][0])[ug] = acc4;
        ((float4*)&part[kc - 1][5][0])[ug] = acc5;
        ((float4*)&part[kc - 1][6][0])[ug] = acc6;
        ((float4*)&part[kc - 1][7][0])[ug] = acc7;
    }
    __syncthreads();
    if (!kc) {
        #pragma unroll
        for (int j = 0; j < 7; ++j) {
            float4 p;
            p = ((float4*)&part[j][0][0])[ug]; acc0.x+=p.x; acc0.y+=p.y; acc0.z+=p.z; acc0.w+=p.w;
            p = ((float4*)&part[j][1][0])[ug]; acc1.x+=p.x; acc1.y+=p.y; acc1.z+=p.z; acc1.w+=p.w;
            p = ((float4*)&part[j][2][0])[ug]; acc2.x+=p.x; acc2.y+=p.y; acc2.z+=p.z; acc2.w+=p.w;
            p = ((float4*)&part[j][3][0])[ug]; acc3.x+=p.x; acc3.y+=p.y; acc3.z+=p.z; acc3.w+=p.w;
            p = ((float4*)&part[j][4][0])[ug]; acc4.x+=p.x; acc4.y+=p.y; acc4.z+=p.z; acc4.w+=p.w;
            p = ((float4*)&part[j][5][0])[ug]; acc5.x+=p.x; acc5.y+=p.y; acc5.z+=p.z; acc5.w+=p.w;
            p = ((float4*)&part[j][6][0])[ug]; acc6.x+=p.x; acc6.y+=p.y; acc6.z+=p.z; acc6.w+=p.w;
            p = ((float4*)&part[j][7][0])[ug]; acc7.x+=p.x; acc7.y+=p.y; acc7.z+=p.z; acc7.w+=p.w;
        }
        #define EXP4(A) A.x=__expf(2.f*A.x); A.y=__expf(2.f*A.y); A.z=__expf(2.f*A.z); A.w=__expf(2.f*A.w);
        EXP4(acc0) EXP4(acc1) EXP4(acc2) EXP4(acc3)
        EXP4(acc4) EXP4(acc5) EXP4(acc6) EXP4(acc7)
        if (which == 0) {
            float4* p = (float4*)(eqp + (size_t)row0 * UU + u0);
            p[0*(UU/4)] = acc0; p[1*(UU/4)] = acc1; p[2*(UU/4)] = acc2; p[3*(UU/4)] = acc3;
            p[4*(UU/4)] = acc4; p[5*(UU/4)] = acc5; p[6*(UU/4)] = acc6; p[7*(UU/4)] = acc7;
        } else {
            int b = row0 >> 8, v0 = row0 & 255;
            #define KSTORE(J, CX) { \
                float4 lo = make_float4(acc0.CX, acc1.CX, acc2.CX, acc3.CX); \
                float4 hi = make_float4(acc4.CX, acc5.CX, acc6.CX, acc7.CX); \
                float* dst = ekT + ((size_t)(b * UU) + u0 + J) * TV + v0;    \
                *(float4*)dst = lo; *(float4*)(dst + 4) = hi; }
            KSTORE(0, x) KSTORE(1, y) KSTORE(2, z) KSTORE(3, w)
        }
    }
}

// ---------------- kernel 2: FUSED scores + masked softmax + context ----------------
// 256 blocks x 1024 thr; block = (b, 4 q-rows). Register-tiled phases,
// flat single-barrier phase-B combine, softmax gated to 4 waves.
__global__ __launch_bounds__(1024) void attn_kernel(
    const float* __restrict__ eqp, const float* __restrict__ ekT,
    const float* __restrict__ scale, const unsigned char* __restrict__ m,
    const float* __restrict__ value,
    float* __restrict__ ctx, float* __restrict__ weights) {
    int blk = blockIdx.x;              // 0..255
    int b = blk >> 6;
    int q0 = (blk & 63) * 4;
    int tid = threadIdx.x;             // 0..1023
    int lane = tid & 63;

    __shared__ float eq4[4][UU];       // 2 KB
    __shared__ float sc2[UU];          // 512 B
    __shared__ union {                 // 56 KB (phases sync-separated)
        float pbA[8][4][TV];           // phase A partials (32 KB)
        float4 pbB[7][4][128];         // phase B flat partials (56 KB)
    } un;
    __shared__ float sv[4][TV];        // 4 KB
    __shared__ float redM[4][4], redS[4][4];
    __shared__ int flagF, flagB;

    if (tid == 0) { flagF = 0; flagB = 0; }
    __syncthreads();
    if (tid < 128) {
        ((float4*)eq4)[tid] = ((const float4*)(eqp + (size_t)(b * TQ + q0) * UU))[tid];
    } else if (tid < 160) {
        float4 s = ((const float4*)scale)[tid - 128];
        ((float4*)sc2)[tid - 128] = make_float4(-2.f*s.x, -2.f*s.y, -2.f*s.z, -2.f*s.w);
    }
    if (tid >= 256 && tid < 512) {     // mask probe, first 1024 B safe all layouts
        uchar4 c4 = ((const uchar4*)m)[tid - 256];
        if (c4.w == 0x3f) flagF = 1;                 // float32 1.0f tail byte
        if (c4.y | c4.z | c4.w) flagB = 1;           // off-word nonzero -> u8
    }
    __syncthreads();

    // ---- phase A: scores s'[r,v] = sum_u (-2 sc_u) * rcp(1 + Eq[r,u]*Ek[u,v]) ----
    {
        int vp = tid & 127;
        int h = tid >> 7;
        const float2* kb2 = (const float2*)(ekT + ((size_t)b * UU + h * 16) * TV) + vp;
        float ax0=0.f, ay0=0.f, ax1=0.f, ay1=0.f;
        float ax2=0.f, ay2=0.f, ax3=0.f, ay3=0.f;
        #pragma unroll
        for (int c = 0; c < 4; ++c) {
            float4 e0 = ((const float4*)&eq4[0][0])[h * 4 + c];
            float4 e1 = ((const float4*)&eq4[1][0])[h * 4 + c];
            float4 e2 = ((const float4*)&eq4[2][0])[h * 4 + c];
            float4 e3 = ((const float4*)&eq4[3][0])[h * 4 + c];
            float4 sc = ((const float4*)sc2)[h * 4 + c];
            #define ASTEP(J, CX) { \
                float2 ek = kb2[(size_t)(c * 4 + J) * (TV / 2)]; \
                ax0 = fmaf(sc.CX, fast_rcp(fmaf(e0.CX, ek.x, 1.f)), ax0); \
                ay0 = fmaf(sc.CX, fast_rcp(fmaf(e0.CX, ek.y, 1.f)), ay0); \
                ax1 = fmaf(sc.CX, fast_rcp(fmaf(e1.CX, ek.x, 1.f)), ax1); \
                ay1 = fmaf(sc.CX, fast_rcp(fmaf(e1.CX, ek.y, 1.f)), ay1); \
                ax2 = fmaf(sc.CX, fast_rcp(fmaf(e2.CX, ek.x, 1.f)), ax2); \
                ay2 = fmaf(sc.CX, fast_rcp(fmaf(e2.CX, ek.y, 1.f)), ay2); \
                ax3 = fmaf(sc.CX, fast_rcp(fmaf(e3.CX, ek.x, 1.f)), ax3); \
                ay3 = fmaf(sc.CX, fast_rcp(fmaf(e3.CX, ek.y, 1.f)), ay3); }
            ASTEP(0, x) ASTEP(1, y) ASTEP(2, z) ASTEP(3, w)
        }
        ((float2*)&un.pbA[h][0][0])[vp] = make_float2(ax0, ay0);
        ((float2*)&un.pbA[h][1][0])[vp] = make_float2(ax1, ay1);
        ((float2*)&un.pbA[h][2][0])[vp] = make_float2(ax2, ay2);
        ((float2*)&un.pbA[h][3][0])[vp] = make_float2(ax3, ay3);
        __syncthreads();
        if (h < 4) {
            float2 s = make_float2(0.f, 0.f);
            #pragma unroll
            for (int g = 0; g < 8; ++g) {
                float2 p = ((float2*)&un.pbA[g][h][0])[vp];
                s.x += p.x; s.y += p.y;
            }
            ((float2*)&sv[h][0])[vp] = s;
        }
        __syncthreads();
    }

    // ---- masked softmax: gated to waves 0-3; barriers outside branches ----
    {
        int v = tid & 255;
        float s0, s1, s2, s3, e0, e1, e2, e3;
        if (tid < 256) {
            float mk;
            {
                int idx = b * TV + v;
                bool ok;
                if (flagF)      ok = (m[4 * idx + 3] != 0);
                else if (flagB) ok = (m[idx] != 0);
                else            ok = (m[4 * idx] != 0);
                mk = ok ? __builtin_inff() : NEGV;
            }
            s0 = fminf(sv[0][v], mk); s1 = fminf(sv[1][v], mk);
            s2 = fminf(sv[2][v], mk); s3 = fminf(sv[3][v], mk);
            float m0 = s0, m1 = s1, m2 = s2, m3 = s3;
            #pragma unroll
            for (int off = 32; off >= 1; off >>= 1) {
                m0 = fmaxf(m0, __shfl_xor(m0, off));
                m1 = fmaxf(m1, __shfl_xor(m1, off));
                m2 = fmaxf(m2, __shfl_xor(m2, off));
                m3 = fmaxf(m3, __shfl_xor(m3, off));
            }
            int wid = tid >> 6;
            if (lane == 0) {
                redM[0][wid] = m0; redM[1][wid] = m1;
                redM[2][wid] = m2; redM[3][wid] = m3;
            }
        }
        __syncthreads();
        if (tid < 256) {
            float f0 = fmaxf(fmaxf(redM[0][0], redM[0][1]), fmaxf(redM[0][2], redM[0][3]));
            float f1 = fmaxf(fmaxf(redM[1][0], redM[1][1]), fmaxf(redM[1][2], redM[1][3]));
            float f2 = fmaxf(fmaxf(redM[2][0], redM[2][1]), fmaxf(redM[2][2], redM[2][3]));
            float f3 = fmaxf(fmaxf(redM[3][0], redM[3][1]), fmaxf(redM[3][2], redM[3][3]));
            e0 = __expf(s0 - f0); e1 = __expf(s1 - f1);
            e2 = __expf(s2 - f2); e3 = __expf(s3 - f3);
            float t0 = e0, t1 = e1, t2 = e2, t3 = e3;
            #pragma unroll
            for (int off = 32; off >= 1; off >>= 1) {
                t0 += __shfl_xor(t0, off); t1 += __shfl_xor(t1, off);
                t2 += __shfl_xor(t2, off); t3 += __shfl_xor(t3, off);
            }
            int wid = tid >> 6;
            if (lane == 0) {
                redS[0][wid] = t0; redS[1][wid] = t1;
                redS[2][wid] = t2; redS[3][wid] = t3;
            }
        }
        __syncthreads();
        if (tid < 256) {
            float r0 = fast_rcp((redS[0][0] + redS[0][1]) + (redS[0][2] + redS[0][3]));
            float r1 = fast_rcp((redS[1][0] + redS[1][1]) + (redS[1][2] + redS[1][3]));
            float r2 = fast_rcp((redS[2][0] + redS[2][1]) + (redS[2][2] + redS[2][3]));
            float r3 = fast_rcp((redS[3][0] + redS[3][1]) + (redS[3][2] + redS[3][3]));
            float w0 = e0 * r0, w1 = e1 * r1, w2 = e2 * r2, w3 = e3 * r3;
            float* wp = weights + (size_t)(b * TQ + q0) * TV + v;
            wp[0 * TV] = w0; wp[1 * TV] = w1; wp[2 * TV] = w2; wp[3 * TV] = w3;
            sv[0][v] = w0; sv[1][v] = w1; sv[2][v] = w2; sv[3][v] = w3;
        }
        __syncthreads();
    }

    // ---- phase B: flat combine (vh 1..7 write pbB; 1 barrier; vh 0 reduces) ----
    {
        int df = tid & 127;
        int vh = tid >> 7;
        const float4* vb4 = (const float4*)(value + ((size_t)b * TV + vh * 32) * DD) + df;
        float4 c0 = make_float4(0.f,0.f,0.f,0.f), c1 = c0, c2 = c0, c3 = c0;
        #pragma unroll
        for (int vc = 0; vc < 8; ++vc) {
            float4 w0 = ((const float4*)&sv[0][0])[vh * 8 + vc];
            float4 w1 = ((const float4*)&sv[1][0])[vh * 8 + vc];
            float4 w2 = ((const float4*)&sv[2][0])[vh * 8 + vc];
            float4 w3 = ((const float4*)&sv[3][0])[vh * 8 + vc];
            #define BSTEP(J, CX) { \
                float4 vv = vb4[(size_t)(vc * 4 + J) * (DD / 4)]; \
                c0 = f4fma(w0.CX, vv, c0); c1 = f4fma(w1.CX, vv, c1); \
                c2 = f4fma(w2.CX, vv, c2); c3 = f4fma(w3.CX, vv, c3); }
            BSTEP(0, x) BSTEP(1, y) BSTEP(2, z) BSTEP(3, w)
        }
        // pbA is dead (last read in phase A, fenced by softmax barriers);
        // pbB does not alias sv -> no barrier needed before the writes.
        if (vh > 0) {
            un.pbB[vh-1][0][df] = c0; un.pbB[vh-1][1][df] = c1;
            un.pbB[vh-1][2][df] = c2; un.pbB[vh-1][3][df] = c3;
        }
        __syncthreads();
        if (vh == 0) {
            #pragma unroll
            for (int j = 0; j < 7; ++j) {
                float4 p;
                p = un.pbB[j][0][df]; c0.x+=p.x; c0.y+=p.y; c0.z+=p.z; c0.w+=p.w;
                p = un.pbB[j][1][df]; c1.x+=p.x; c1.y+=p.y; c1.z+=p.z; c1.w+=p.w;
                p = un.pbB[j][2][df]; c2.x+=p.x; c2.y+=p.y; c2.z+=p.z; c2.w+=p.w;
                p = un.pbB[j][3][df]; c3.x+=p.x; c3.y+=p.y; c3.z+=p.z; c3.w+=p.w;
            }
            ((float4*)(ctx + (size_t)(b * TQ + q0 + 0) * DD))[df] = c0;
            ((float4*)(ctx + (size_t)(b * TQ + q0 + 1) * DD))[df] = c1;
            ((float4*)(ctx + (size_t)(b * TQ + q0 + 2) * DD))[df] = c2;
            ((float4*)(ctx + (size_t)(b * TQ + q0 + 3) * DD))[df] = c3;
        }
    }
}

extern "C" void kernel_launch(void* const* d_in, const int* in_sizes, int n_in,
                              void* d_out, int out_size, void* d_ws, size_t ws_size,
                              hipStream_t stream) {
    const float* query = (const float*)d_in[0];
    const float* value = (const float*)d_in[1];
    const unsigned char* mask = (const unsigned char*)d_in[2];
    const float* W1 = (const float*)d_in[3];
    const float* W2 = (const float*)d_in[4];
    const float* scale = (const float*)d_in[5];

    float* ctx = (float*)d_out;                              // [B,TQ,D]
    float* weights = (float*)d_out + (size_t)BB * TQ * DD;   // [B,TQ,TV]

    float* eqp = (float*)d_ws;                               // 512 KB
    float* ekT = eqp + (size_t)BB * TQ * UU;                 // 512 KB

    proj_kernel<<<256, 256, 0, stream>>>(query, value, W1, W2, eqp, ekT);
    attn_kernel<<<256, 1024, 0, stream>>>(eqp, ekT, scale, mask, value, ctx, weights);
}